// Round 12
// baseline (400.742 us; speedup 1.0000x reference)
//
#include <hip/hip_runtime.h>

typedef float f2 __attribute__((ext_vector_type(2)));

constexpr int Tt = 512;    // sequence length
constexpr int Bb = 256;    // batch
constexpr int Ee = 200;    // word-embedding dim
constexpr int Gg = 96;     // 4*H
constexpr int Vv = 50000;  // vocab

__device__ __forceinline__ float fast_rcp(float x) { return __builtin_amdgcn_rcpf(x); }
__device__ __forceinline__ float sigf(float x) { return fast_rcp(1.f + __expf(-x)); }
__device__ __forceinline__ float tanhf_(float x) {
    float e = __expf(2.f * x);
    return 1.f - 2.f * fast_rcp(e + 1.f);
}

// ---------------------------------------------------------------------------
// Kernel A: EwW[w][j*4+c] = sum_k Ew[w][k] * Wl[k][c*24+j]   (gate-interleaved)
// UNCHANGED (3rd round byte-identical): becomes top dispatch next round so
// its counters finally become visible for an evidence-based fix.
// ---------------------------------------------------------------------------
__global__ __launch_bounds__(256) void ew_proj(const float* __restrict__ Ew,
                                               const float* __restrict__ Wl,
                                               float* __restrict__ EwW)
{
    __shared__ float As[8][64];   // [k][m]
    __shared__ float Bs[8][96];   // [k][gate-interleaved col]
    const int tid = threadIdx.x;
    const int w0  = blockIdx.x * 64;
    const int tr  = tid >> 4;        // 0..15 -> rows tr*4..+3
    const int tc  = tid & 15;        // 0..15 -> cols tc*6..+5
    const int am  = tid >> 2;        // 0..63  (A stage row)
    const int ak  = (tid & 3) * 2;   // 0,2,4,6 (A stage k pair)
    const int bk  = tid >> 5;        // 0..7   (B stage k)
    const int bg  = (tid & 31) * 3;  // 0..93  (B stage col group)

    const int wA = w0 + am;
    const float* aptr = Ew + (long)((wA < Vv) ? wA : (Vv - 1)) * Ee + ak;
    const float* bptr = Wl + bk * Gg + bg;
    int gp[3];
    #pragma unroll
    for (int u = 0; u < 3; ++u) { const int g = bg + u; gp[u] = (g % 24) * 4 + g / 24; }

    // prologue: stage k0=0 tile into registers
    f2    avr  = *(const f2*)(aptr);
    float bvr0 = bptr[0], bvr1 = bptr[1], bvr2 = bptr[2];

    f2 acc[4][3] = {};

    for (int k0 = 0; k0 < Ee; k0 += 8) {
        // write staged registers to LDS
        As[ak][am]     = avr.x;
        As[ak + 1][am] = avr.y;
        Bs[bk][gp[0]] = bvr0; Bs[bk][gp[1]] = bvr1; Bs[bk][gp[2]] = bvr2;
        __syncthreads();

        // issue next tile's loads — latency hidden under compute below
        if (k0 + 8 < Ee) {
            avr  = *(const f2*)(aptr + k0 + 8);
            const long bo = (long)(k0 + 8) * Gg;
            bvr0 = bptr[bo + 0]; bvr1 = bptr[bo + 1]; bvr2 = bptr[bo + 2];
        }

        #pragma unroll
        for (int kk = 0; kk < 8; ++kk) {
            const float4 a4 = *(const float4*)&As[kk][tr * 4];
            f2 b[3];
            #pragma unroll
            for (int u = 0; u < 3; ++u) b[u] = *(const f2*)&Bs[kk][tc * 6 + u * 2];
            #pragma unroll
            for (int i = 0; i < 4; ++i) {
                const float ai = (&a4.x)[i];
                f2 a2 = {ai, ai};
                #pragma unroll
                for (int u = 0; u < 3; ++u) acc[i][u] += a2 * b[u];
            }
        }
        __syncthreads();
    }
    #pragma unroll
    for (int i = 0; i < 4; ++i) {
        const int w = w0 + tr * 4 + i;
        if (w < Vv) {
            #pragma unroll
            for (int u = 0; u < 3; ++u)
                *(f2*)(EwW + (long)w * Gg + tc * 6 + u * 2) = acc[i][u];
        }
    }
}

// ---------------------------------------------------------------------------
// Kernel C v4: sequential LSTM + mean-pool + MLP head.
// 1 chain per wave (grid=256). Lane u<24 owns all 4 gates of unit u.
// U weights live in LDS (gate-interleaved [k][u*4+c]): rounds 8/10/11 proved
// LLVM will NOT keep 96 loop-invariant floats in VGPRs (remat/spill every
// iteration regardless of source-level pins). LDS reads are remat-immune:
// one ds_read_b128 per k, SAME vaddr (u*16) with k*384 immediate offset.
// h-broadcast stays v_readlane (VALU, no DS latency on the serial path).
// ---------------------------------------------------------------------------
#define REP24(M) M(0)M(1)M(2)M(3)M(4)M(5)M(6)M(7)M(8)M(9)M(10)M(11) \
                 M(12)M(13)M(14)M(15)M(16)M(17)M(18)M(19)M(20)M(21)M(22)M(23)

__global__ __launch_bounds__(64, 1) void lstm_head(
    const int* __restrict__ words, const int* __restrict__ caps,
    const float* __restrict__ Ec,  const float* __restrict__ Wl,
    const float* __restrict__ bl,  const float* __restrict__ EwW,
    const float* __restrict__ W1,  const float* __restrict__ b1,
    const float* __restrict__ W2,  const float* __restrict__ b2,
    float* __restrict__ out)
{
    __shared__ float  Uls[24 * 96];   // [k][u*4+c] gate-interleaved, 9 KB
    __shared__ float4 EcB[3][24];     // cap -> per-unit (i,j,f,o) incl. b_lstm
    __shared__ float  hmean[24];
    __shared__ float  a1buf[50];

    const int lane = threadIdx.x;
    const int u    = (lane < 24) ? lane : 23;   // clamp; lanes>=24 shadow lane 23
    const int b    = blockIdx.x;

    // stage U into LDS: Uls[k*96 + u*4 + c] = Wl[(203+k)*96 + c*24 + u]
    for (int e = lane; e < 24 * 96; e += 64) {
        const int k = e / 96, g = e % 96;
        Uls[e] = Wl[(203 + k) * Gg + (g & 3) * 24 + (g >> 2)];
    }
    // EcB[cap][unit] = Ec[cap] @ Wl[200:203] + b_lstm   (gate-interleaved)
    for (int e = lane; e < 72; e += 64) {
        const int cap = e / 24, jj = e % 24;
        float4 v;
        #pragma unroll
        for (int c = 0; c < 4; ++c) {
            float s = bl[c * 24 + jj];
            #pragma unroll
            for (int kk = 0; kk < 3; ++kk)
                s += Ec[cap * 3 + kk] * Wl[(200 + kk) * Gg + c * 24 + jj];
            (&v.x)[c] = s;
        }
        EcB[cap][jj] = v;
    }
    __syncthreads();

    const int* wrow = words + b * Tt;
    const int* crow = caps  + b * Tt;
    const int  off  = u * 4;
    const float* Ub = Uls + off;      // lane-fixed base; per-k = imm offset k*384B

    // software pipeline: x ready for t..t+2, issued at t for t+3
    float4 x0 = *(const float4*)(EwW + (long)wrow[0] * Gg + off);
    float4 x1 = *(const float4*)(EwW + (long)wrow[1] * Gg + off);
    float4 x2 = *(const float4*)(EwW + (long)wrow[2] * Gg + off);
    int wi3 = wrow[3], wi4 = wrow[4];
    int cp0 = crow[0], cp1 = crow[1], cp2 = crow[2], cp3 = crow[3], cp4 = crow[4];

    float4 ecb = EcB[cp0][u];
    float cst = 0.f, hsum = 0.f, hn = 0.f;

    for (int t = 0; t < Tt; ++t) {
        // issue gather for t+3, index loads for t+5 (latency-tolerant)
        const float4 x3 = *(const float4*)(EwW + (long)wi3 * Gg + off);
        const int tn  = (t + 5 < Tt) ? (t + 5) : (Tt - 1);
        const int win = wrow[tn];
        const int cpn = crow[tn];

        float zi = x0.x + ecb.x;
        float zj = x0.y + ecb.y;
        float zf = x0.z + ecb.z;
        float zo = x0.w + ecb.w;

        const int hni = __float_as_int(hn);  // h[k] lives in lane k
#define KSTEP(K) { const float4 uk_ = *(const float4*)(Ub + (K) * 96);   \
                   const float hk_ = __int_as_float(                     \
                       __builtin_amdgcn_readlane(hni, K));               \
                   zi += hk_ * uk_.x;  zj += hk_ * uk_.y;                \
                   zf += hk_ * uk_.z;  zo += hk_ * uk_.w; }
        REP24(KSTEP)
#undef KSTEP

        const float ig = sigf(zi);
        const float tj = tanhf_(zj);
        const float fg = sigf(zf + 1.0f);   // forget bias
        const float og = sigf(zo);
        cst = fg * cst + ig * tj;
        hn  = og * tanhf_(cst);
        hsum += hn;

        // prefetch next step's cap add-in, rotate pipeline
        ecb = EcB[cp1][u];
        x0 = x1; x1 = x2; x2 = x3;
        wi3 = wi4; wi4 = win;
        cp0 = cp1; cp1 = cp2; cp2 = cp3; cp3 = cp4; cp4 = cpn;
    }

    // ---- epilogue: mean-pool + MLP head -----------------------------------
    if (lane < 24) hmean[lane] = hsum * (1.f / (float)Tt);
    __syncthreads();

    if (lane < 50) {
        float s = b1[lane];
        #pragma unroll
        for (int k = 0; k < 24; ++k)
            s += hmean[k] * W1[k * 50 + lane];
        a1buf[lane] = (s > 0.f) ? s : (__expf(s) - 1.f);  // ELU
    }
    __syncthreads();

    if (lane < 6) {
        float s = b2[lane];
        for (int q = 0; q < 50; ++q) s += a1buf[q] * W2[q * 6 + lane];
        out[b * 6 + lane] = sigf(s);
    }
}

// ---------------------------------------------------------------------------
extern "C" void kernel_launch(void* const* d_in, const int* in_sizes, int n_in,
                              void* d_out, int out_size, void* d_ws, size_t ws_size,
                              hipStream_t stream)
{
    const int*   words = (const int*)d_in[0];
    const int*   caps  = (const int*)d_in[1];
    const float* Ew    = (const float*)d_in[2];
    const float* Ec    = (const float*)d_in[3];
    const float* Wl    = (const float*)d_in[4];
    const float* bl    = (const float*)d_in[5];
    const float* W1    = (const float*)d_in[6];
    const float* b1    = (const float*)d_in[7];
    const float* W2    = (const float*)d_in[8];
    const float* b2    = (const float*)d_in[9];
    float* out = (float*)d_out;
    float* EwW = (float*)d_ws;   // 50000 * 96 floats = 19.2 MB scratch

    ew_proj<<<(Vv + 63) / 64, 256, 0, stream>>>(Ew, Wl, EwW);
    lstm_head<<<Bb, 64, 0, stream>>>(words, caps, Ec, Wl, bl, EwW,
                                     W1, b1, W2, b2, out);
}